// Round 2
// baseline (410.836 us; speedup 1.0000x reference)
//
#include <hip/hip_runtime.h>

// PCEN: M[0]=x[0]; M[t]=(1-s)M[t-1]+s*x[t]; out=(x/(M+eps)^a + d)^r - d^r
// x, out: (64, 4000, 128) fp32.
//
// R6: single-pass fused kernel (R5 post-mortem: wall insensitive to kernel
// issue-rate; remaining lever is traffic — read x ONCE instead of twice).
//  - 2048 one-wave blocks, one (b,chunk) each; chunk (125 x 128 fp32 = 64 KB)
//    staged in LDS during the phase-1 local scan (2 blocks/CU).
//  - ticket-ordered decoupled lookback (rocPRIM pattern): blocks take a global
//    atomic ticket; ticket -> (ck = t>>6, b = t&63), so every dependency has a
//    strictly lower ticket = a block that was already executing. Phase 1 has no
//    dependencies, so every running block publishes -> deadlock-free without
//    any dispatch-order or co-residency assumption.
//  - lookback truncated to 8 predecessors: A_C^8 ~ 1e-11 << absmax 0.0039.
//  - agent-scope atomics (payload relaxed u64, flag release/acquire) handle
//    cross-XCD L2 non-coherence.
//  - phase 2 re-scans from LDS (2-way bank alias = free) and emits PCEN via
//    nontemporal stores. x is read exactly once from HBM (NT loads).
// ws layout: [0,8192) flags (2048 u32, (b*32+ck)); [8192] ticket; bend u64
// payload at +16384 (1 MB). First 12 KB re-zeroed per launch via memset.

typedef float v2f __attribute__((ext_vector_type(2)));

#define B_DIM 64
#define T_DIM 4000
#define F_DIM 128
#define F2    (F_DIM / 2)     // row stride in float2 units
#define NCHUNK 32
#define CLEN 125              // NCHUNK*CLEN == T_DIM
#define PF 25                 // prefetch depth; CLEN = 5*PF
#define NG (CLEN / PF)        // 5 groups
#define LOOKBACK 8            // A_C^8 ~ 1e-11: far below tolerance
#define A_C 0.04222576f       // 0.975^125, computed in double, rounded to fp32

__device__ __forceinline__ float pcen_out(float xv, float M) {
    const float EPS = 1e-6f, NALPHA = -0.98f, DELTA = 2.0f, SQRTD = 1.41421356237f;
    float p = __builtin_amdgcn_exp2f(NALPHA * __builtin_amdgcn_logf(M + EPS));
    return __builtin_sqrtf(__builtin_fmaf(xv, p, DELTA)) - SQRTD;
}

__global__ __launch_bounds__(64) void pcen_fused(const float* __restrict__ x,
                                                 float* __restrict__ out,
                                                 unsigned int* __restrict__ hdr,
                                                 unsigned long long* __restrict__ bend) {
    const float S = 0.025f, OMS = 0.975f;
    __shared__ v2f xs[CLEN * F2];          // 64 000 B: the staged chunk
    const int lane = threadIdx.x;          // 0..63, float2 lane = 2 features

    // Ticket: execution-order virtual block id -> ck ascends with time.
    unsigned int tk = 0;
    if (lane == 0)
        tk = __hip_atomic_fetch_add(&hdr[B_DIM * NCHUNK], 1u,
                                    __ATOMIC_RELAXED, __HIP_MEMORY_SCOPE_AGENT);
    tk = (unsigned int)__shfl((int)tk, 0);
    const int ck = (int)(tk >> 6);         // 0..31, monotone in ticket order
    const int b  = (int)(tk & 63u);
    const int t0 = ck * CLEN;
    const v2f* xb = (const v2f*)(x + (size_t)b * T_DIM * F_DIM) + lane;
    const float first = (ck == 0) ? 1.0f : S;   // exact M[0]=x[0] rule

    // ---- phase 1: stream chunk HBM -> LDS, local zero-init scan -----------
    v2f buf[PF];
    #pragma unroll
    for (int u = 0; u < PF; ++u)
        buf[u] = __builtin_nontemporal_load(&xb[(t0 + u) * F2]);

    float Mx = 0.0f, My = 0.0f;
    #pragma unroll
    for (int g = 0; g < NG; ++g) {
        #pragma unroll
        for (int u = 0; u < PF; ++u) {
            const int s = g * PF + u;
            const v2f xv = buf[u];
            xs[s * F2 + lane] = xv;                       // ds_write_b64
            const float ms = (s == 0) ? first : S;
            Mx = __builtin_fmaf(OMS, Mx, ms * xv.x);
            My = __builtin_fmaf(OMS, My, ms * xv.y);
            if (g + 1 < NG)
                buf[u] = __builtin_nontemporal_load(&xb[(t0 + s + PF) * F2]);
        }
    }

    // ---- publish chunk-end partial (payload then release flag) ------------
    union { v2f v; unsigned long long u; } pk;
    pk.v = (v2f){Mx, My};
    __hip_atomic_store(&bend[((size_t)b * NCHUNK + ck) * 64 + lane], pk.u,
                       __ATOMIC_RELAXED, __HIP_MEMORY_SCOPE_AGENT);
    if (lane == 0)
        __hip_atomic_store(&hdr[b * NCHUNK + ck], 1u,
                           __ATOMIC_RELEASE, __HIP_MEMORY_SCOPE_AGENT);

    // ---- truncated lookback: carry from <=8 nearest predecessors ----------
    float Cx = 0.0f, Cy = 0.0f;
    if (ck > 0) {
        int j0 = ck - LOOKBACK; if (j0 < 0) j0 = 0;
        float coef = 1.0f;                  // A_C^(ck-1-j), j descending
        for (int j = ck - 1; j >= j0; --j) {
            unsigned int* fp = &hdr[b * NCHUNK + j];
            while (__hip_atomic_load(fp, __ATOMIC_ACQUIRE,
                                     __HIP_MEMORY_SCOPE_AGENT) == 0u)
                __builtin_amdgcn_s_sleep(2);
            union { unsigned long long u; v2f v; } w;
            w.u = __hip_atomic_load(&bend[((size_t)b * NCHUNK + j) * 64 + lane],
                                    __ATOMIC_RELAXED, __HIP_MEMORY_SCOPE_AGENT);
            Cx = __builtin_fmaf(coef, w.v.x, Cx);
            Cy = __builtin_fmaf(coef, w.v.y, Cy);
            coef *= A_C;
        }
    }

    // ---- phase 2: exact re-scan from LDS with carry, emit PCEN ------------
    float M2x = Cx, M2y = Cy;
    v2f* ob = (v2f*)(out + (size_t)b * T_DIM * F_DIM) + lane;
    #pragma unroll 5
    for (int s = 0; s < CLEN; ++s) {
        const v2f xv = xs[s * F2 + lane];                 // ds_read_b64
        const float ms = (s == 0) ? first : S;
        M2x = __builtin_fmaf(OMS, M2x, ms * xv.x);
        M2y = __builtin_fmaf(OMS, M2y, ms * xv.y);
        v2f o;
        o.x = pcen_out(xv.x, M2x);
        o.y = pcen_out(xv.y, M2y);
        // nontemporal: out is never re-read
        __builtin_nontemporal_store(o, &ob[(t0 + s) * F2]);
    }
}

extern "C" void kernel_launch(void* const* d_in, const int* in_sizes, int n_in,
                              void* d_out, int out_size, void* d_ws, size_t ws_size,
                              hipStream_t stream) {
    const float* x = (const float*)d_in[0];
    float* out = (float*)d_out;
    unsigned int* hdr = (unsigned int*)d_ws;                       // flags + ticket
    unsigned long long* bend = (unsigned long long*)((char*)d_ws + 16384);
    // Re-zero flags + ticket every launch (graph-capture-safe async memset).
    hipMemsetAsync(d_ws, 0, 12288, stream);
    pcen_fused<<<dim3(B_DIM * NCHUNK), 64, 0, stream>>>(x, out, hdr, bend);
}

// Round 3
// 342.304 us; speedup vs baseline: 1.2002x; 1.2002x over previous
//
#include <hip/hip_runtime.h>

// PCEN: M[0]=x[0]; M[t]=(1-s)M[t-1]+s*x[t]; out=(x/(M+eps)^a + d)^r - d^r
// x, out: (64, 4000, 128) fp32.
//
// R7: R6's fused single-pass (read x ONCE, LDS-staged chunk, ticket-ordered
// truncated lookback) with the sync pathology fixed.
// R6 post-mortem: kernel ran 245 us @ 538 GB/s because the lookback spin
// polled with agent-scope ACQUIRE -> every poll emits a cache invalidate;
// 2048 blocks polling = continuous L1/L2 invalidation storm across all XCDs,
// killing cachability for every streaming wave. Fix:
//  - poll flags RELAXED (no invalidate), s_sleep between polls;
//  - ONE fence(acquire, agent) after all flags observed, before payloads;
//  - publisher: payload relaxed -> fence(release, agent) -> flag relaxed.
// Data path unchanged from R6 (passed, absmax 0.00390625):
//  - 2048 one-wave blocks, one (b,chunk) each; chunk (125x128 fp32 = 64 KB)
//    staged in LDS during the phase-1 local scan (2 blocks/CU).
//  - ticket-ordered lookback: every dependency has a strictly lower ticket =
//    a block already executing; phase 1 has no deps so every running block
//    publishes -> deadlock-free with no dispatch-order assumption.
//  - lookback truncated to 8 predecessors: A_C^8 ~ 1e-11 << tolerance.
//  - phase 2 re-scans from LDS (2-way bank alias = free), emits via NT stores.
// ws: [0,8192) flags; [8192] ticket; +16384: bend u64 payload (1 MB).
// First 12 KB re-zeroed per launch via hipMemsetAsync (graph-capture-safe).

typedef float v2f __attribute__((ext_vector_type(2)));

#define B_DIM 64
#define T_DIM 4000
#define F_DIM 128
#define F2    (F_DIM / 2)     // row stride in float2 units
#define NCHUNK 32
#define CLEN 125              // NCHUNK*CLEN == T_DIM
#define PF 25                 // prefetch depth; CLEN = 5*PF
#define NG (CLEN / PF)        // 5 groups
#define LOOKBACK 8            // A_C^8 ~ 1e-11: far below tolerance
#define A_C 0.04222576f       // 0.975^125, computed in double, rounded to fp32

__device__ __forceinline__ float pcen_out(float xv, float M) {
    const float EPS = 1e-6f, NALPHA = -0.98f, DELTA = 2.0f, SQRTD = 1.41421356237f;
    float p = __builtin_amdgcn_exp2f(NALPHA * __builtin_amdgcn_logf(M + EPS));
    return __builtin_sqrtf(__builtin_fmaf(xv, p, DELTA)) - SQRTD;
}

__global__ __launch_bounds__(64) void pcen_fused(const float* __restrict__ x,
                                                 float* __restrict__ out,
                                                 unsigned int* __restrict__ hdr,
                                                 unsigned long long* __restrict__ bend) {
    const float S = 0.025f, OMS = 0.975f;
    __shared__ v2f xs[CLEN * F2];          // 64 000 B: the staged chunk
    const int lane = threadIdx.x;          // 0..63, float2 lane = 2 features

    // Ticket: execution-order virtual block id -> ck ascends with time.
    unsigned int tk = 0;
    if (lane == 0)
        tk = __hip_atomic_fetch_add(&hdr[B_DIM * NCHUNK], 1u,
                                    __ATOMIC_RELAXED, __HIP_MEMORY_SCOPE_AGENT);
    tk = (unsigned int)__shfl((int)tk, 0);
    const int ck = (int)(tk >> 6);         // 0..31, monotone in ticket order
    const int b  = (int)(tk & 63u);
    const int t0 = ck * CLEN;
    const v2f* xb = (const v2f*)(x + (size_t)b * T_DIM * F_DIM) + lane;
    const float first = (ck == 0) ? 1.0f : S;   // exact M[0]=x[0] rule

    // ---- phase 1: stream chunk HBM -> LDS, local zero-init scan -----------
    v2f buf[PF];
    #pragma unroll
    for (int u = 0; u < PF; ++u)
        buf[u] = __builtin_nontemporal_load(&xb[(t0 + u) * F2]);

    float Mx = 0.0f, My = 0.0f;
    #pragma unroll
    for (int g = 0; g < NG; ++g) {
        #pragma unroll
        for (int u = 0; u < PF; ++u) {
            const int s = g * PF + u;
            const v2f xv = buf[u];
            xs[s * F2 + lane] = xv;                       // ds_write_b64
            const float ms = (s == 0) ? first : S;
            Mx = __builtin_fmaf(OMS, Mx, ms * xv.x);
            My = __builtin_fmaf(OMS, My, ms * xv.y);
            if (g + 1 < NG)
                buf[u] = __builtin_nontemporal_load(&xb[(t0 + s + PF) * F2]);
        }
    }

    // ---- publish chunk-end partial: payload -> release fence -> flag ------
    union { v2f v; unsigned long long u; } pk;
    pk.v = (v2f){Mx, My};
    __hip_atomic_store(&bend[((size_t)b * NCHUNK + ck) * 64 + lane], pk.u,
                       __ATOMIC_RELAXED, __HIP_MEMORY_SCOPE_AGENT);
    __builtin_amdgcn_fence(__ATOMIC_RELEASE, "agent");
    if (lane == 0)
        __hip_atomic_store(&hdr[b * NCHUNK + ck], 1u,
                           __ATOMIC_RELAXED, __HIP_MEMORY_SCOPE_AGENT);

    // ---- truncated lookback: carry from <=8 nearest predecessors ----------
    float Cx = 0.0f, Cy = 0.0f;
    if (ck > 0) {
        int j0 = ck - LOOKBACK; if (j0 < 0) j0 = 0;
        // 1) wait for all needed flags with RELAXED polls (no cache inv).
        for (int j = ck - 1; j >= j0; --j) {
            unsigned int* fp = &hdr[b * NCHUNK + j];
            while (__hip_atomic_load(fp, __ATOMIC_RELAXED,
                                     __HIP_MEMORY_SCOPE_AGENT) == 0u)
                __builtin_amdgcn_s_sleep(16);
        }
        // 2) one acquire fence, then read all payloads.
        __builtin_amdgcn_fence(__ATOMIC_ACQUIRE, "agent");
        float coef = 1.0f;                  // A_C^(ck-1-j), j descending
        for (int j = ck - 1; j >= j0; --j) {
            union { unsigned long long u; v2f v; } w;
            w.u = __hip_atomic_load(&bend[((size_t)b * NCHUNK + j) * 64 + lane],
                                    __ATOMIC_RELAXED, __HIP_MEMORY_SCOPE_AGENT);
            Cx = __builtin_fmaf(coef, w.v.x, Cx);
            Cy = __builtin_fmaf(coef, w.v.y, Cy);
            coef *= A_C;
        }
    }

    // ---- phase 2: exact re-scan from LDS with carry, emit PCEN ------------
    float M2x = Cx, M2y = Cy;
    v2f* ob = (v2f*)(out + (size_t)b * T_DIM * F_DIM) + lane;
    #pragma unroll 5
    for (int s = 0; s < CLEN; ++s) {
        const v2f xv = xs[s * F2 + lane];                 // ds_read_b64
        const float ms = (s == 0) ? first : S;
        M2x = __builtin_fmaf(OMS, M2x, ms * xv.x);
        M2y = __builtin_fmaf(OMS, M2y, ms * xv.y);
        v2f o;
        o.x = pcen_out(xv.x, M2x);
        o.y = pcen_out(xv.y, M2y);
        // nontemporal: out is never re-read
        __builtin_nontemporal_store(o, &ob[(t0 + s) * F2]);
    }
}

extern "C" void kernel_launch(void* const* d_in, const int* in_sizes, int n_in,
                              void* d_out, int out_size, void* d_ws, size_t ws_size,
                              hipStream_t stream) {
    const float* x = (const float*)d_in[0];
    float* out = (float*)d_out;
    unsigned int* hdr = (unsigned int*)d_ws;                       // flags + ticket
    unsigned long long* bend = (unsigned long long*)((char*)d_ws + 16384);
    // Re-zero flags + ticket every launch (graph-capture-safe async memset).
    hipMemsetAsync(d_ws, 0, 12288, stream);
    pcen_fused<<<dim3(B_DIM * NCHUNK), 64, 0, stream>>>(x, out, hdr, bend);
}